// Round 1
// baseline (623.747 us; speedup 1.0000x reference)
//
#include <hip/hip_runtime.h>
#include <math.h>

#define DIM 2400
#define VEC (DIM / 4)      // 600 float4 per row
#define EPS 1e-6f
#define MARGIN 1.0f
#define NPOS 5

// ---------------------------------------------------------------------------
// Kernel 1: compute d_ap[p] = ||anchor - pos[p] + EPS||_2 for p in [0,5),
// and zero the output accumulator. One wave per positive row (5 waves).
// ---------------------------------------------------------------------------
__global__ void dap_kernel(const float* __restrict__ anchor,
                           const float* __restrict__ pos,
                           float* __restrict__ dap,
                           float* __restrict__ out) {
    const int lane = threadIdx.x & 63;
    const int wave = threadIdx.x >> 6;          // 0..4
    const float4* a4 = (const float4*)anchor;
    const float4* p4 = (const float4*)(pos + wave * DIM);

    float acc = 0.0f;
    for (int w = lane; w < VEC; w += 64) {
        float4 a = a4[w];
        float4 b = p4[w];
        float dx = a.x - b.x + EPS;
        float dy = a.y - b.y + EPS;
        float dz = a.z - b.z + EPS;
        float dw = a.w - b.w + EPS;
        acc = fmaf(dx, dx, fmaf(dy, dy, fmaf(dz, dz, fmaf(dw, dw, acc))));
    }
    #pragma unroll
    for (int off = 32; off > 0; off >>= 1)
        acc += __shfl_down(acc, off, 64);
    if (lane == 0) dap[wave] = sqrtf(acc);
    if (threadIdx.x == 0) *out = 0.0f;
}

// ---------------------------------------------------------------------------
// Kernel 2: one wave per negative row, grid-stride over rows.
// loss += relu(d_ap[row % 5] - ||anchor - neg[row] + EPS|| + MARGIN)
// Per-block reduction -> one atomicAdd per block.
// ---------------------------------------------------------------------------
__global__ __launch_bounds__(256, 4)
void triplet_kernel(const float* __restrict__ anchor,
                    const float* __restrict__ neg,
                    const float* __restrict__ dap,
                    float* __restrict__ out,
                    int n_rows) {
    __shared__ float4 s_anchor[VEC];            // 9.6 KB
    __shared__ float  s_dap[NPOS];
    __shared__ float  s_partial[4];             // one slot per wave

    for (int i = threadIdx.x; i < VEC; i += blockDim.x)
        s_anchor[i] = ((const float4*)anchor)[i];
    if (threadIdx.x < NPOS)
        s_dap[threadIdx.x] = dap[threadIdx.x];
    __syncthreads();

    const int lane = threadIdx.x & 63;
    const int wave = threadIdx.x >> 6;
    const int waves_per_block = blockDim.x >> 6;
    const int stride = gridDim.x * waves_per_block;

    float local = 0.0f;
    for (int row = blockIdx.x * waves_per_block + wave; row < n_rows; row += stride) {
        const float4* nr = (const float4*)(neg + (size_t)row * DIM);
        float acc = 0.0f;
        #pragma unroll 3
        for (int w = lane; w < VEC; w += 64) {
            float4 a = s_anchor[w];
            float4 b = nr[w];
            float dx = a.x - b.x + EPS;
            float dy = a.y - b.y + EPS;
            float dz = a.z - b.z + EPS;
            float dw = a.w - b.w + EPS;
            acc = fmaf(dx, dx, fmaf(dy, dy, fmaf(dz, dz, fmaf(dw, dw, acc))));
        }
        #pragma unroll
        for (int off = 32; off > 0; off >>= 1)
            acc += __shfl_down(acc, off, 64);
        if (lane == 0) {
            float d_an = sqrtf(acc);
            float t = s_dap[row % NPOS] - d_an + MARGIN;
            local += fmaxf(t, 0.0f);
        }
    }

    if (lane == 0) s_partial[wave] = local;
    __syncthreads();
    if (threadIdx.x == 0) {
        float blocksum = 0.0f;
        for (int w = 0; w < waves_per_block; ++w) blocksum += s_partial[w];
        atomicAdd(out, blocksum);
    }
}

extern "C" void kernel_launch(void* const* d_in, const int* in_sizes, int n_in,
                              void* d_out, int out_size, void* d_ws, size_t ws_size,
                              hipStream_t stream) {
    const float* anchor = (const float*)d_in[0];
    const float* pos    = (const float*)d_in[1];
    const float* neg    = (const float*)d_in[2];
    float* out = (float*)d_out;
    float* dap = (float*)d_ws;                  // 5 floats of scratch

    const int n_neg  = in_sizes[2] / DIM;       // 50000
    const int n_rows = (n_neg / NPOS) * NPOS;   // full chunks only

    dap_kernel<<<1, NPOS * 64, 0, stream>>>(anchor, pos, dap, out);

    const int block = 256;
    const int waves_per_block = block / 64;
    int grid = 2048;
    int max_grid = (n_rows + waves_per_block - 1) / waves_per_block;
    if (grid > max_grid) grid = max_grid;
    triplet_kernel<<<grid, block, 0, stream>>>(anchor, neg, dap, out, n_rows);
}